// Round 5
// baseline (334.031 us; speedup 1.0000x reference)
//
#include <hip/hip_runtime.h>
#include <math.h>

// ConvSlimCapsule3D fused, round 5: 512-thread blocks (4 waves/SIMD), division-free
// pipelined staging, B-frag register double-buffer. Math identical to round 4.
// Block = 16 voxels (b,d,h,wseg): slab (10zy x 18j x 128ch f16, swizzled) in LDS;
// conv = M128 x N128 x K448 (14 chunks x 32) mfma_f32_16x16x32_f16, barrier-free
// K-loop; votes in separate LDS region; routing = 4 lanes per (v,o) pair.

typedef _Float16 half8 __attribute__((ext_vector_type(8)));
typedef _Float16 half4 __attribute__((ext_vector_type(4)));
typedef float f32x4 __attribute__((ext_vector_type(4)));

// ---- prep: cw f32 (n=128, ca=16, tap=27) -> wh2 f16 [n][c=14][k=32], k = tp*16+ca,
//      tap = 2c+tp, tap 27 zeroed (matches A-side zero row zy=9). ----
__global__ __launch_bounds__(256) void prep_weights(const float* __restrict__ cw,
                                                    _Float16* __restrict__ wh2) {
    const int idx = blockIdx.x * 256 + threadIdx.x;   // 57344
    const int n   = idx / 448;
    const int rem = idx - n * 448;
    const int c   = rem >> 5;
    const int k   = rem & 31;
    const int tp  = k >> 4, ca = k & 15;
    const int tap = 2 * c + tp;
    float v = (tap < 27) ? cw[n * 432 + ca * 27 + tap] : 0.0f;
    wh2[idx] = (_Float16)v;
}

// slab byte offset: [zy 0..9][j 0..17][unit 0..15]*16B, unit swizzled by j
__device__ __forceinline__ int slab_off_b(int zy, int j, int ch) {
    const int u = ch >> 3;
    return zy * 4608 + j * 256 + ((u ^ (j & 15)) << 4) + ((ch & 7) << 1);
}

__global__ __launch_bounds__(512, 4) void caps_mfma_kernel(
    const float* __restrict__ x,      // (2,8,16,32,32,32) f32
    const _Float16* __restrict__ wh2, // (128,14,32) f16 reordered
    const float* __restrict__ cb,     // (128,)
    const float* __restrict__ bias,   // (8,16)
    float* __restrict__ out)          // (2,8,16,32,32,32) f32
{
    __shared__ half8 slabv[2880];     // 46080 B: x slab (read-only after staging)
    __shared__ half8 vhv[2064];       // 33024 B: votes; RT/LG overlay when dead
    char* smem = (char*)slabv;
    _Float16* Vh = (_Float16*)vhv;
    float* RT = (float*)vhv;          // floats 0..1151 of vote region
    float* LG = (float*)vhv + 1152;   // floats 1152..2303

    const int t    = threadIdx.x;     // 0..511
    const int gid  = blockIdx.x;      // 4096
    const int wseg = gid & 1;
    const int h    = (gid >> 1) & 31;
    const int d    = (gid >> 6) & 31;
    const int b    = gid >> 11;
    const int w0g  = wseg << 4;

    const float* xb = x + (size_t)b * 4194304;

    // ========== stage slab, interior: 1280 rows x 4 segs, division-free ==========
    // row = (zy 0..9)*128 + ch; 4 lanes/row load contiguous 64 B (j = 1..16)
    #pragma unroll
    for (int it2 = 0; it2 < 10; it2++) {
        const int sid = t + it2 * 512;        // 0..5119
        const int row = sid >> 2;
        const int seg = sid & 3;
        const int zyr = row >> 7;             // 0..9 (9 = zero row)
        const int ch  = row & 127;
        const int dz  = zyr / 3;
        const int dy  = zyr - dz * 3;
        const int z   = d + dz - 1;
        const int y   = h + dy - 1;
        const bool rv = (zyr < 9) && ((unsigned)z < 32u) && ((unsigned)y < 32u);
        f32x4 val = (f32x4)0.f;
        if (rv)
            val = *(const f32x4*)(xb + (size_t)ch * 32768 + z * 1024 + y * 32
                                  + w0g + seg * 4);   // 16B aligned
        #pragma unroll
        for (int e = 0; e < 4; e++)
            *(_Float16*)(smem + slab_off_b(zyr, seg * 4 + 1 + e, ch)) = (_Float16)val[e];
    }
    // ---- edge pass: one real edge elem + one zero elem per row ----
    #pragma unroll
    for (int it2 = 0; it2 < 3; it2++) {
        const int row = t + it2 * 512;
        if (row < 1280) {
            const int zyr = row >> 7;
            const int ch  = row & 127;
            const int dz  = zyr / 3;
            const int dy  = zyr - dz * 3;
            const int z   = d + dz - 1;
            const int y   = h + dy - 1;
            const bool rv = (zyr < 9) && ((unsigned)z < 32u) && ((unsigned)y < 32u);
            const int wsc = (w0g == 0) ? 16 : 15;     // real edge w
            const int jsc = (w0g == 0) ? 17 : 0;
            const int jz  = (w0g == 0) ? 0  : 17;     // zero-pad j
            float v = 0.f;
            if (rv) v = xb[(size_t)ch * 32768 + z * 1024 + y * 32 + wsc];
            *(_Float16*)(smem + slab_off_b(zyr, jsc, ch)) = (_Float16)v;
            *(_Float16*)(smem + slab_off_b(zyr, jz,  ch)) = (_Float16)0.f;
        }
    }
    __syncthreads();   // B0: slab fully staged

    // ========== GEMM: M=128, N=128, K=448 (14 chunks), no inner barriers =========
    const int wid = t >> 6, lane = t & 63;
    const int q = lane >> 4, r = lane & 15;
    const int wy = wid >> 1, wx = wid & 1;    // wy 0..3 (M), wx 0..1 (N)
    const int qlow = q & 1, tphase = q >> 1;

    int zyA[14], dxA[14];
    #pragma unroll
    for (int c = 0; c < 14; c++) {
        const int tap = 2 * c + tphase;       // tap 27 -> zy 9 (zero row)
        const int dz = tap / 9, r9 = tap - dz * 9;
        const int dy = r9 / 3,  dxx = r9 - dy * 3;
        zyA[c] = dz * 3 + dy;
        dxA[c] = dxx;
    }
    int uA[2];
    #pragma unroll
    for (int mt = 0; mt < 2; mt++) uA[mt] = (wy * 2 + mt) * 2 + qlow;  // ch-unit

    const _Float16* bp[4];
    #pragma unroll
    for (int nt = 0; nt < 4; nt++)
        bp[nt] = wh2 + (wx * 64 + nt * 16 + r) * 448 + q * 8;

    f32x4 acc[2][4];
    #pragma unroll
    for (int i = 0; i < 2; i++)
        #pragma unroll
        for (int j = 0; j < 4; j++) acc[i][j] = (f32x4)0.f;

    half8 bf[2][4];
    #pragma unroll
    for (int nt = 0; nt < 4; nt++) bf[0][nt] = *(const half8*)(bp[nt]);

    #pragma unroll
    for (int c = 0; c < 14; c++) {
        const int cur = c & 1;
        if (c < 13) {
            #pragma unroll
            for (int nt = 0; nt < 4; nt++)
                bf[cur ^ 1][nt] = *(const half8*)(bp[nt] + (c + 1) * 32);
        }
        const int jw = r + dxA[c];
        const int rowb = zyA[c] * 4608 + jw * 256;
        const int js = jw & 15;
        half8 af[2];
        #pragma unroll
        for (int mt = 0; mt < 2; mt++)
            af[mt] = *(const half8*)(smem + rowb + ((uA[mt] ^ js) << 4));
        #pragma unroll
        for (int mt = 0; mt < 2; mt++)
            #pragma unroll
            for (int nt = 0; nt < 4; nt++)
                acc[mt][nt] = __builtin_amdgcn_mfma_f32_16x16x32_f16(
                    af[mt], bf[cur][nt], acc[mt][nt], 0, 0, 0);
    }

    // ========== epilogue: votes (+conv bias) f16 into own region =================
    float cbv[4];
    #pragma unroll
    for (int nt = 0; nt < 4; nt++) cbv[nt] = cb[wx * 64 + nt * 16 + r];
    #pragma unroll
    for (int mt = 0; mt < 2; mt++) {
        #pragma unroll
        for (int nt = 0; nt < 4; nt++) {
            const int n = wx * 64 + nt * 16 + r;
            #pragma unroll
            for (int reg = 0; reg < 4; reg++) {
                const int v = q * 4 + reg;          // C/D row = q*4+reg
                const int i = wy * 2 + mt;
                Vh[v * 1032 + i * 128 + n] = (_Float16)(acc[mt][nt][reg] + cbv[nt]);
            }
        }
    }
    __syncthreads();   // B2: all vote writes visible

    // ========== routing: 512 threads = 128 (v,o) pairs x 4 atom-quarters =========
    const int p  = t >> 2, qd = t & 3;
    const int vv = p & 15, oo = p >> 4;   // also coop-softmax task (v2=vv, i2=oo)

    float vf[8][4];
    #pragma unroll
    for (int i = 0; i < 8; i++) {
        const half4 hv = *(const half4*)&Vh[vv * 1032 + i * 128 + oo * 16 + qd * 4];
        #pragma unroll
        for (int a = 0; a < 4; a++) vf[i][a] = (float)hv[a];
    }
    __syncthreads();   // B3: vote reads done -> RT/LG may overlay vote region

    float vn[8];
    #pragma unroll
    for (int i = 0; i < 8; i++) {
        float s = 0.f;
        #pragma unroll
        for (int a = 0; a < 4; a++) s = fmaf(vf[i][a], vf[i][a], s);
        s += __shfl_xor(s, 1);
        s += __shfl_xor(s, 2);
        vn[i] = sqrtf(s);
    }
    float bl[4];
    #pragma unroll
    for (int a = 0; a < 4; a++) bl[a] = bias[oo * 16 + qd * 4 + a];

    float rt[8], lgr[8], pre[4];
    #pragma unroll
    for (int i = 0; i < 8; i++) { rt[i] = 0.125f; lgr[i] = 0.f; }

    for (int it = 0; it < 3; it++) {
        #pragma unroll
        for (int a = 0; a < 4; a++) {
            float s = bl[a];
            #pragma unroll
            for (int i = 0; i < 8; i++) s = fmaf(rt[i], vf[i][a], s);
            pre[a] = s;
        }
        if (it == 2) break;

        float s2 = 0.f;
        #pragma unroll
        for (int a = 0; a < 4; a++) s2 = fmaf(pre[a], pre[a], s2);
        s2 += __shfl_xor(s2, 1);
        s2 += __shfl_xor(s2, 2);
        const float pn = sqrtf(s2);

        #pragma unroll
        for (int i = 0; i < 8; i++) {
            float dp = 0.f;
            #pragma unroll
            for (int a = 0; a < 4; a++) dp = fmaf(pre[a], vf[i][a], dp);
            dp += __shfl_xor(dp, 1);
            dp += __shfl_xor(dp, 2);
            lgr[i] += dp / fmaxf(pn * vn[i], 1e-8f);
        }
        if (qd == 0) {
            #pragma unroll
            for (int i = 0; i < 8; i++) LG[vv * 72 + i * 8 + oo] = lgr[i];
        }
        __syncthreads();   // LG writes visible

        // coop softmax over o for task (v2=vv, i2=oo), 2 o's per lane
        {
            float ex[2], ps = 0.f;
            #pragma unroll
            for (int k = 0; k < 2; k++) {
                ex[k] = __expf(LG[vv * 72 + oo * 8 + qd * 2 + k]);
                ps += ex[k];
            }
            ps += __shfl_xor(ps, 1);
            ps += __shfl_xor(ps, 2);
            const float rs = 1.f / ps;
            #pragma unroll
            for (int k = 0; k < 2; k++)
                RT[vv * 72 + oo * 8 + qd * 2 + k] = ex[k] * rs;
        }
        __syncthreads();   // RT writes visible

        #pragma unroll
        for (int i = 0; i < 8; i++) rt[i] = RT[vv * 72 + i * 8 + oo];
    }

    // ---- squash + store (4 atoms per thread) ----
    float s2 = 0.f;
    #pragma unroll
    for (int a = 0; a < 4; a++) s2 = fmaf(pre[a], pre[a], s2);
    s2 += __shfl_xor(s2, 1);
    s2 += __shfl_xor(s2, 2);
    const float nn = sqrtf(s2);
    const float scale = (s2 / (1.f + s2)) / (nn + 1e-12f);
    const size_t sp = (size_t)d * 1024 + h * 32 + w0g + vv;
    #pragma unroll
    for (int a = 0; a < 4; a++)
        out[((size_t)((b * 8 + oo) * 16 + qd * 4 + a)) * 32768 + sp] = pre[a] * scale;
}

extern "C" void kernel_launch(void* const* d_in, const int* in_sizes, int n_in,
                              void* d_out, int out_size, void* d_ws, size_t ws_size,
                              hipStream_t stream) {
    const float* x    = (const float*)d_in[0];
    const float* cw   = (const float*)d_in[1];
    const float* cb   = (const float*)d_in[2];
    const float* bias = (const float*)d_in[3];
    float* out = (float*)d_out;
    _Float16* wh2 = (_Float16*)d_ws;   // 57344 * 2 = 114688 B

    hipLaunchKernelGGL(prep_weights, dim3(224), dim3(256), 0, stream, cw, wh2);
    hipLaunchKernelGGL(caps_mfma_kernel, dim3(4096), dim3(512), 0, stream,
                       x, wh2, cb, bias, out);
}